// Round 1
// baseline (172.564 us; speedup 1.0000x reference)
//
#include <hip/hip_runtime.h>

// Problem constants (match reference setup_inputs)
#define MM 100000   // frames
#define CC 24       // cameras
#define FPB 8       // frames per block
#define BLK (FPB * CC)  // 192 threads

// cam[c] layout: 0:fx 1:fy 2:u0 3:v0 4..8:k1,k2,p1,p2,k3 9..17:R(row-major) 18..20:t
__global__ __launch_bounds__(BLK) void ba_reproj_kernel(
    const float* __restrict__ pole3d,   // [M,3,3]
    const float* __restrict__ pole2d,   // [M,C,3,2]
    const float* __restrict__ Kmat,     // [C,3,3]
    const float* __restrict__ dist,     // [C,5]
    const float* __restrict__ Rmat,     // [C,3,3]
    const float* __restrict__ tvec,     // [C,3]
    const int*   __restrict__ mask,     // [M,C]
    float* __restrict__ out)            // scalar accumulator
{
    __shared__ float cam[CC][21];
    __shared__ float p3[FPB][9];
    __shared__ float red_s[BLK];
    __shared__ float red_w[BLK];
    __shared__ float frame_loss[FPB];

    const int tid = threadIdx.x;

    // Stage camera parameters (504 floats) into LDS
    for (int i = tid; i < CC * 21; i += BLK) {
        const int c = i / 21, j = i % 21;
        float v;
        if      (j == 0) v = Kmat[c * 9 + 0];          // fx
        else if (j == 1) v = Kmat[c * 9 + 4];          // fy
        else if (j == 2) v = Kmat[c * 9 + 2];          // u0
        else if (j == 3) v = Kmat[c * 9 + 5];          // v0
        else if (j <  9) v = dist[c * 5 + (j - 4)];    // k1,k2,p1,p2,k3
        else if (j < 18) v = Rmat[c * 9 + (j - 9)];    // R row-major
        else             v = tvec[c * 3 + (j - 18)];   // t
        cam[c][j] = v;
    }

    const int m0 = blockIdx.x * FPB;
    // Stage this block's 8 frames of pole3d (72 floats)
    for (int i = tid; i < FPB * 9; i += BLK) {
        p3[i / 9][i % 9] = pole3d[(size_t)m0 * 9 + i];
    }
    __syncthreads();

    const int f = tid / CC;   // frame within block
    const int c = tid % CC;   // camera
    const int m = m0 + f;

    const float* cm = cam[c];
    const float fx = cm[0], fy = cm[1], u0 = cm[2], v0 = cm[3];
    const float k1 = cm[4], k2 = cm[5], p1 = cm[6], p2 = cm[7], k3 = cm[8];

    // pole2d[m,c,p,:] — 24 contiguous bytes per thread, coalesced across the wave
    const float2* pd = (const float2*)(pole2d + ((size_t)m * CC + c) * 6);
    float2 q0 = pd[0], q1 = pd[1], q2 = pd[2];
    const float obs[3][2] = {{q0.x, q0.y}, {q1.x, q1.y}, {q2.x, q2.y}};

    float s = 0.f;
    #pragma unroll
    for (int p = 0; p < 3; ++p) {
        const float X = p3[f][p * 3 + 0], Y = p3[f][p * 3 + 1], Z = p3[f][p * 3 + 2];
        const float xc = cm[ 9] * X + cm[10] * Y + cm[11] * Z + cm[18];
        const float yc = cm[12] * X + cm[13] * Y + cm[14] * Z + cm[19];
        const float zc = cm[15] * X + cm[16] * Y + cm[17] * Z + cm[20];
        const float inv = 1.f / zc;
        const float x0 = xc * inv, x1 = yc * inv;
        const float r2 = x0 * x0 + x1 * x1;
        const float radial = 1.f + r2 * (k1 + r2 * (k2 + r2 * k3));
        const float xu = x0 * radial + 2.f * p1 * x0 * x1 + p2 * (r2 + 2.f * x0 * x0);
        const float yu = x1 * radial + p1 * (r2 + 2.f * x1 * x1) + 2.f * p2 * x0 * x1;
        const float u = fx * xu + u0;
        const float v = fy * yu + v0;
        const float dx = obs[p][0] - u;
        const float dy = obs[p][1] - v;
        s += sqrtf(dx * dx + dy * dy);
    }
    s *= (1.f / 3.f);

    const float w = (float)mask[(size_t)m * CC + c];
    red_s[tid] = s * w;
    red_w[tid] = w;
    __syncthreads();

    // Per-frame segmented reduction over 24 cameras
    if (c == 0) {
        float ss = 0.f, ww = 0.f;
        #pragma unroll
        for (int j = 0; j < CC; ++j) { ss += red_s[f * CC + j]; ww += red_w[f * CC + j]; }
        frame_loss[f] = ss / ww;   // mask guarantees ww >= 1
    }
    __syncthreads();

    if (tid == 0) {
        float bl = 0.f;
        #pragma unroll
        for (int j = 0; j < FPB; ++j) bl += frame_loss[j];
        atomicAdd(out, bl * (1.0f / MM));
    }
}

extern "C" void kernel_launch(void* const* d_in, const int* in_sizes, int n_in,
                              void* d_out, int out_size, void* d_ws, size_t ws_size,
                              hipStream_t stream) {
    const float* pole3d = (const float*)d_in[0];
    const float* pole2d = (const float*)d_in[1];
    const float* Kmat   = (const float*)d_in[2];
    const float* dist   = (const float*)d_in[3];
    const float* Rmat   = (const float*)d_in[4];
    const float* tvec   = (const float*)d_in[5];
    // d_in[6] = pole (unused: LINE_W = LENGTH_W = 0)
    const int*   mask   = (const int*)d_in[7];
    float* out = (float*)d_out;

    // Harness poisons d_out with 0xAA and does not re-zero between replays.
    hipMemsetAsync(out, 0, sizeof(float), stream);

    const int nblocks = MM / FPB;  // 12500
    ba_reproj_kernel<<<nblocks, BLK, 0, stream>>>(
        pole3d, pole2d, Kmat, dist, Rmat, tvec, mask, out);
}

// Round 2
// 31.350 us; speedup vs baseline: 5.5044x; 5.5044x over previous
//
#include <hip/hip_runtime.h>

// Problem constants (match reference setup_inputs)
#define MM 100000            // frames
#define CC 24                // cameras
#define FPB 8                // frames per block-iteration
#define BLK (FPB * CC)       // 192 threads
#define NGROUPS (MM / FPB)   // 12500 frame-groups
#define GRID 2048            // persistent blocks: 8 per CU on 256 CUs

// cam[c] layout: 0:fx 1:fy 2:u0 3:v0 4..8:k1,k2,p1,p2,k3 9..17:R(row-major) 18..20:t
__global__ __launch_bounds__(BLK) void ba_main_kernel(
    const float* __restrict__ pole3d,   // [M,3,3]
    const float* __restrict__ pole2d,   // [M,C,3,2]
    const float* __restrict__ Kmat,     // [C,3,3]
    const float* __restrict__ dist,     // [C,5]
    const float* __restrict__ Rmat,     // [C,3,3]
    const float* __restrict__ tvec,     // [C,3]
    const int*   __restrict__ mask,     // [M,C]
    float* __restrict__ ws)             // [GRID] per-block partial sums
{
    __shared__ float cam[CC][21];
    __shared__ float p3[FPB][9];
    __shared__ float red_s[BLK];
    __shared__ float red_w[BLK];

    const int tid = threadIdx.x;

    // Stage camera parameters (504 floats) into LDS — ONCE per block
    for (int i = tid; i < CC * 21; i += BLK) {
        const int c = i / 21, j = i % 21;
        float v;
        if      (j == 0) v = Kmat[c * 9 + 0];          // fx
        else if (j == 1) v = Kmat[c * 9 + 4];          // fy
        else if (j == 2) v = Kmat[c * 9 + 2];          // u0
        else if (j == 3) v = Kmat[c * 9 + 5];          // v0
        else if (j <  9) v = dist[c * 5 + (j - 4)];    // k1,k2,p1,p2,k3
        else if (j < 18) v = Rmat[c * 9 + (j - 9)];    // R row-major
        else             v = tvec[c * 3 + (j - 18)];   // t
        cam[c][j] = v;
    }

    const int f = tid / CC;   // frame within group
    const int c = tid % CC;   // camera

    const float* cm = cam[c];   // stable LDS pointer (cam written before first barrier use)

    float block_sum = 0.f;      // accumulated by threads tid < FPB

    for (int g = blockIdx.x; g < NGROUPS; g += GRID) {
        const int m0 = g * FPB;

        // Stage this group's 8 frames of pole3d (72 floats, coalesced)
        for (int i = tid; i < FPB * 9; i += BLK) {
            p3[i / 9][i % 9] = pole3d[(size_t)m0 * 9 + i];
        }
        __syncthreads();   // p3 + (first iter) cam visible

        const int m = m0 + f;
        const float fx = cm[0], fy = cm[1], u0 = cm[2], v0 = cm[3];
        const float k1 = cm[4], k2 = cm[5], p1 = cm[6], p2 = cm[7], k3 = cm[8];

        // pole2d[m,c,:,:] — 24 contiguous bytes/thread, coalesced across the wave
        const float2* pd = (const float2*)(pole2d + ((size_t)m0 * CC + tid) * 6);
        const float2 q0 = pd[0], q1 = pd[1], q2 = pd[2];
        const float obs[3][2] = {{q0.x, q0.y}, {q1.x, q1.y}, {q2.x, q2.y}};

        float s = 0.f;
        #pragma unroll
        for (int p = 0; p < 3; ++p) {
            const float X = p3[f][p * 3 + 0], Y = p3[f][p * 3 + 1], Z = p3[f][p * 3 + 2];
            const float xc = cm[ 9] * X + cm[10] * Y + cm[11] * Z + cm[18];
            const float yc = cm[12] * X + cm[13] * Y + cm[14] * Z + cm[19];
            const float zc = cm[15] * X + cm[16] * Y + cm[17] * Z + cm[20];
            const float inv = 1.f / zc;
            const float x0 = xc * inv, x1 = yc * inv;
            const float r2 = x0 * x0 + x1 * x1;
            const float radial = 1.f + r2 * (k1 + r2 * (k2 + r2 * k3));
            const float xu = x0 * radial + 2.f * p1 * x0 * x1 + p2 * (r2 + 2.f * x0 * x0);
            const float yu = x1 * radial + p1 * (r2 + 2.f * x1 * x1) + 2.f * p2 * x0 * x1;
            const float u = fx * xu + u0;
            const float v = fy * yu + v0;
            const float dx = obs[p][0] - u;
            const float dy = obs[p][1] - v;
            s += sqrtf(dx * dx + dy * dy);
        }
        s *= (1.f / 3.f);

        const float w = (float)mask[(size_t)m0 * CC + tid];
        red_s[tid] = s * w;
        red_w[tid] = w;
        __syncthreads();

        // Per-frame segmented reduction over 24 cameras (8 parallel lanes)
        if (tid < FPB) {
            float ss = 0.f, ww = 0.f;
            #pragma unroll
            for (int j = 0; j < CC; ++j) { ss += red_s[tid * CC + j]; ww += red_w[tid * CC + j]; }
            block_sum += ss / ww;   // mask guarantees ww >= 1
        }
        __syncthreads();   // protect red_s/red_w + p3 before next iteration overwrites
    }

    // Combine the 8 per-frame-lane accumulators via LDS (reuse red_s)
    red_s[tid] = (tid < FPB) ? block_sum : 0.f;
    __syncthreads();
    if (tid == 0) {
        float bl = 0.f;
        #pragma unroll
        for (int j = 0; j < FPB; ++j) bl += red_s[j];
        ws[blockIdx.x] = bl;
    }
}

__global__ __launch_bounds__(256) void ba_reduce_kernel(
    const float* __restrict__ ws, float* __restrict__ out)
{
    __shared__ float sh[256];
    float s = 0.f;
    for (int i = threadIdx.x; i < GRID; i += 256) s += ws[i];
    sh[threadIdx.x] = s;
    __syncthreads();
    #pragma unroll
    for (int st = 128; st > 0; st >>= 1) {
        if (threadIdx.x < st) sh[threadIdx.x] += sh[threadIdx.x + st];
        __syncthreads();
    }
    if (threadIdx.x == 0) out[0] = sh[0] * (1.0f / MM);
}

extern "C" void kernel_launch(void* const* d_in, const int* in_sizes, int n_in,
                              void* d_out, int out_size, void* d_ws, size_t ws_size,
                              hipStream_t stream) {
    const float* pole3d = (const float*)d_in[0];
    const float* pole2d = (const float*)d_in[1];
    const float* Kmat   = (const float*)d_in[2];
    const float* dist   = (const float*)d_in[3];
    const float* Rmat   = (const float*)d_in[4];
    const float* tvec   = (const float*)d_in[5];
    // d_in[6] = pole (unused: LINE_W = LENGTH_W = 0)
    const int*   mask   = (const int*)d_in[7];
    float* out = (float*)d_out;
    float* ws  = (float*)d_ws;   // GRID floats = 8 KB

    ba_main_kernel<<<GRID, BLK, 0, stream>>>(
        pole3d, pole2d, Kmat, dist, Rmat, tvec, mask, ws);
    ba_reduce_kernel<<<1, 256, 0, stream>>>(ws, out);
}

// Round 3
// 28.508 us; speedup vs baseline: 6.0532x; 1.0997x over previous
//
#include <hip/hip_runtime.h>

// Problem constants (match reference setup_inputs)
#define MM 100000            // frames
#define CC 24                // cameras
#define BLK 256              // 4 waves per block
#define WPB (BLK / 64)       // waves per block
#define GRID 1280            // persistent blocks (~5/CU)
#define NW (GRID * WPB)      // total waves = 5120
#define NP (MM / 2)          // frame-pairs = 50000 (each wave-iter does 2 frames)

struct Pack {
    float2 a0, a1, a2;   // observed pixels for 3 points
    float  w;            // mask weight (0 for idle lanes)
    float  q[9];         // pole3d of this half-wave's frame
};

__device__ __forceinline__ Pack load_pack(
    const float* __restrict__ pole3d, const float* __restrict__ pole2d,
    const int* __restrict__ mask, int m, int c, float active)
{
    Pack pk;
    const float2* pd = (const float2*)(pole2d + ((size_t)m * CC + c) * 6);
    pk.a0 = pd[0]; pk.a1 = pd[1]; pk.a2 = pd[2];
    pk.w = active * (float)mask[(size_t)m * CC + c];
    const float* q = pole3d + (size_t)m * 9;
    #pragma unroll
    for (int i = 0; i < 9; ++i) pk.q[i] = q[i];   // same addr across 32 lanes -> broadcast
    return pk;
}

__global__ __launch_bounds__(BLK) void ba_main_kernel(
    const float* __restrict__ pole3d,   // [M,3,3]
    const float* __restrict__ pole2d,   // [M,C,3,2]
    const float* __restrict__ Kmat,     // [C,3,3]
    const float* __restrict__ dist,     // [C,5]
    const float* __restrict__ Rmat,     // [C,3,3]
    const float* __restrict__ tvec,     // [C,3]
    const int*   __restrict__ mask,     // [M,C]
    float* __restrict__ ws)             // [GRID] per-block partials
{
    const int tid  = threadIdx.x;
    const int lane = tid & 63;
    const int half = lane >> 5;               // which frame of the pair
    const int cl   = lane & 31;               // camera lane 0..31
    const int c    = (cl < CC) ? cl : (CC - 1);
    const float active = (cl < CC) ? 1.f : 0.f;

    // Per-lane camera parameters in registers (loaded once per block lifetime)
    const float fx = Kmat[c * 9 + 0], fy = Kmat[c * 9 + 4];
    const float u0 = Kmat[c * 9 + 2], v0 = Kmat[c * 9 + 5];
    const float k1 = dist[c * 5 + 0], k2 = dist[c * 5 + 1];
    const float p1 = dist[c * 5 + 2], p2 = dist[c * 5 + 3], k3 = dist[c * 5 + 4];
    const float r00 = Rmat[c * 9 + 0], r01 = Rmat[c * 9 + 1], r02 = Rmat[c * 9 + 2];
    const float r10 = Rmat[c * 9 + 3], r11 = Rmat[c * 9 + 4], r12 = Rmat[c * 9 + 5];
    const float r20 = Rmat[c * 9 + 6], r21 = Rmat[c * 9 + 7], r22 = Rmat[c * 9 + 8];
    const float t0 = tvec[c * 3 + 0], t1 = tvec[c * 3 + 1], t2 = tvec[c * 3 + 2];

    const int wid = blockIdx.x * WPB + (tid >> 6);   // global wave id

    float acc = 0.f;

    // Prologue: prefetch first pair
    Pack cur = load_pack(pole3d, pole2d, mask, 2 * wid + half, c, active);

    for (int p = wid; p < NP; p += NW) {
        // Prefetch next pair (clamped to a valid pair; result discarded if OOB)
        const int pn = p + NW;
        const int pc = (pn < NP) ? pn : wid;
        Pack nxt = load_pack(pole3d, pole2d, mask, 2 * pc + half, c, active);

        // Compute on cur
        float s = 0.f;
        const float2 obs[3] = {cur.a0, cur.a1, cur.a2};
        #pragma unroll
        for (int i = 0; i < 3; ++i) {
            const float X = cur.q[3 * i + 0], Y = cur.q[3 * i + 1], Z = cur.q[3 * i + 2];
            const float xc = r00 * X + r01 * Y + r02 * Z + t0;
            const float yc = r10 * X + r11 * Y + r12 * Z + t1;
            const float zc = r20 * X + r21 * Y + r22 * Z + t2;
            const float inv = __builtin_amdgcn_rcpf(zc);
            const float x0 = xc * inv, x1 = yc * inv;
            const float r2 = x0 * x0 + x1 * x1;
            const float radial = 1.f + r2 * (k1 + r2 * (k2 + r2 * k3));
            const float xu = x0 * radial + 2.f * p1 * x0 * x1 + p2 * (r2 + 2.f * x0 * x0);
            const float yu = x1 * radial + p1 * (r2 + 2.f * x1 * x1) + 2.f * p2 * x0 * x1;
            const float u = fx * xu + u0;
            const float v = fy * yu + v0;
            const float dx = obs[i].x - u;
            const float dy = obs[i].y - v;
            s += __builtin_amdgcn_sqrtf(dx * dx + dy * dy);
        }
        s *= (1.f / 3.f);

        // Masked camera reduction within the 32-lane half (idle lanes contribute 0)
        float ss = s * cur.w;
        float ww = cur.w;
        #pragma unroll
        for (int d = 1; d < 32; d <<= 1) {
            ss += __shfl_xor(ss, d);
            ww += __shfl_xor(ww, d);
        }
        acc += ss * __builtin_amdgcn_rcpf(ww);   // frame loss; ww in [1,24]

        cur = nxt;
    }

    // Combine the two halves (within-half lanes hold identical acc)
    float tot = acc + __shfl_xor(acc, 32);

    // One value per wave -> LDS -> one value per block
    __shared__ float sh[WPB];
    if (lane == 0) sh[tid >> 6] = tot;
    __syncthreads();
    if (tid == 0) {
        float bl = 0.f;
        #pragma unroll
        for (int j = 0; j < WPB; ++j) bl += sh[j];
        ws[blockIdx.x] = bl;
    }
}

__global__ __launch_bounds__(256) void ba_reduce_kernel(
    const float* __restrict__ ws, float* __restrict__ out)
{
    __shared__ float sh[256];
    float s = 0.f;
    for (int i = threadIdx.x; i < GRID; i += 256) s += ws[i];
    sh[threadIdx.x] = s;
    __syncthreads();
    #pragma unroll
    for (int st = 128; st > 0; st >>= 1) {
        if (threadIdx.x < st) sh[threadIdx.x] += sh[threadIdx.x + st];
        __syncthreads();
    }
    if (threadIdx.x == 0) out[0] = sh[0] * (1.0f / MM);
}

extern "C" void kernel_launch(void* const* d_in, const int* in_sizes, int n_in,
                              void* d_out, int out_size, void* d_ws, size_t ws_size,
                              hipStream_t stream) {
    const float* pole3d = (const float*)d_in[0];
    const float* pole2d = (const float*)d_in[1];
    const float* Kmat   = (const float*)d_in[2];
    const float* dist   = (const float*)d_in[3];
    const float* Rmat   = (const float*)d_in[4];
    const float* tvec   = (const float*)d_in[5];
    // d_in[6] = pole (unused: LINE_W = LENGTH_W = 0)
    const int*   mask   = (const int*)d_in[7];
    float* out = (float*)d_out;
    float* ws  = (float*)d_ws;   // GRID floats = 5 KB

    ba_main_kernel<<<GRID, BLK, 0, stream>>>(
        pole3d, pole2d, Kmat, dist, Rmat, tvec, mask, ws);
    ba_reduce_kernel<<<1, 256, 0, stream>>>(ws, out);
}